// Round 12
// baseline (381.965 us; speedup 1.0000x reference)
//
#include <hip/hip_runtime.h>
#include <hip/hip_bf16.h>

namespace {
constexpr int B = 64, L = 1024, D = 64;
constexpr int QS = 16;                // q rows per step (one MFMA tile)
constexpr int QSPLIT = 4;             // q quarters -> 4-way O atomics
constexpr int QRANGE = L / QSPLIT;    // 256
constexpr int NSTEP = QRANGE / QS;    // 16
constexpr int GP = 1028;              // gbuf pitch (f32 words); 4*GP%32=16 -> 2-way max
constexpr int MP = 1040;              // mbuf pitch (bytes)
constexpr unsigned GBUF_B = 2u * QS * GP * 4u;        // 131584 (gate dbuf)
constexpr unsigned LDS_BYTES = GBUF_B + QS * MP;      // +16640 = 148224

typedef float f32x4 __attribute__((ext_vector_type(4)));
typedef int   i32x4 __attribute__((ext_vector_type(4)));
typedef __bf16 bf16x4 __attribute__((ext_vector_type(4)));
typedef __bf16 bf16x8 __attribute__((ext_vector_type(8)));
typedef unsigned int u32;
}  // namespace

// Prep: QT[b][q][d]=bf16(Q/8); KT[b][k][d]=bf16(K); VT[b][d][q]=bf16(V^T).
__global__ __launch_bounds__(256)
void prep_kernel(const float* __restrict__ qp, const float* __restrict__ kp,
                 const float* __restrict__ vp, __bf16* __restrict__ qt,
                 __bf16* __restrict__ kt, __bf16* __restrict__ vt) {
  __shared__ float t[64][65];
  const int tid = threadIdx.x;
  const int b = blockIdx.y;
  const int qb = blockIdx.x * 64;

  {  // V tile -> LDS (f32, padded)
    const int qr = tid >> 4, d0 = (tid & 15) * 4;
#pragma unroll
    for (int p = 0; p < 4; ++p) {
      f32x4 r = *reinterpret_cast<const f32x4*>(
          vp + ((size_t)(b * L + qb + p * 16 + qr)) * D + d0);
      *reinterpret_cast<f32x4*>(&t[p * 16 + qr][d0]) = r;
    }
  }
  {  // Q (scaled 1/8) and K (unscaled) bf16 row conversions
    const int qr = tid >> 2, quad = tid & 3;
    const size_t row = (size_t)(b * L + qb + qr);
    const float* qsrc = qp + row * D + quad * 16;
    const float* ksrc = kp + row * D + quad * 16;
    __bf16* qdst = qt + (row << 6) + quad * 16;
    __bf16* kdst = kt + (row << 6) + quad * 16;
#pragma unroll
    for (int h = 0; h < 2; ++h) {
      f32x4 a = *reinterpret_cast<const f32x4*>(qsrc + h * 8);
      f32x4 bb = *reinterpret_cast<const f32x4*>(qsrc + h * 8 + 4);
      a *= 0.125f; bb *= 0.125f;
      bf16x8 r;
#pragma unroll
      for (int j = 0; j < 4; ++j) { r[j] = (__bf16)a[j]; r[4 + j] = (__bf16)bb[j]; }
      *reinterpret_cast<bf16x8*>(qdst + h * 8) = r;
      f32x4 ka = *reinterpret_cast<const f32x4*>(ksrc + h * 8);
      f32x4 kb = *reinterpret_cast<const f32x4*>(ksrc + h * 8 + 4);
      bf16x8 kr;
#pragma unroll
      for (int j = 0; j < 4; ++j) { kr[j] = (__bf16)ka[j]; kr[4 + j] = (__bf16)kb[j]; }
      *reinterpret_cast<bf16x8*>(kdst + h * 8) = kr;
    }
  }
  __syncthreads();
  {  // transposed V out: VT rows = d, contiguous q
    const int qh = tid & 7, dr = tid >> 3;
#pragma unroll
    for (int p = 0; p < 2; ++p) {
      const int d = p * 32 + dr;
      bf16x8 r;
#pragma unroll
      for (int j = 0; j < 8; ++j) r[j] = (__bf16)t[qh * 8 + j][d];
      *reinterpret_cast<bf16x8*>(vt + (((size_t)(b * D + d)) << 10) + qb + qh * 8) = r;
    }
  }
}

// Main: block = (batch, 256-q quarter), FULL 1024-k rows -> gate/mask/attn
// streams are perfectly linear. 256 blocks = 1/CU, 16 waves. Per 16-q step:
// S = mfma(Q,K) (frag [q-rows][k-cols]); sigmoid in frag layout (gate from
// gbuf, mask byte from mbuf); attn written in place to gbuf, coop-written
// back as full 4KB linear rows. P stays IN REGISTERS: the sigma-permuted
// K-dim (q = 16*(j>>2)+4g+(j&3)) makes the S-frag bit-identical to GEMM2's
// A-fragment; V gathered with the same sigma from VT. Gate staged by
// global_load_lds (double-buffered), drained by counted vmcnt(4) - never 0.
__global__ __launch_bounds__(1024, 1)
void gated_attn_kernel(const __bf16* __restrict__ qt,
                       const __bf16* __restrict__ kt,
                       const __bf16* __restrict__ vt,
                       const int* __restrict__ mask,
                       const float* __restrict__ gate,
                       float* __restrict__ out_o,
                       float* __restrict__ out_attn) {
  extern __shared__ char smem[];
  float* gbuf = reinterpret_cast<float*>(smem);                     // [2][QS][GP]
  unsigned char* mbuf = reinterpret_cast<unsigned char*>(smem + GBUF_B);  // [QS][MP]

  const int tid = threadIdx.x, w = tid >> 6, lane = tid & 63;
  const int c = lane & 15, g = lane >> 4;

  // Decode: each XCD serves 8 batches; all 4 q-quarters of a batch colocate.
  const int i = blockIdx.x;
  const int b = (i & 7) * 8 + ((i >> 3) & 7);
  const int qbase = (i >> 6) * QRANGE;
  const int wkb = w * 64;  // this wave's 64-k strip

  f32x4 acc[4][4] = {};    // O[k = wkb+ks*16+4g+r][d = ds*16+c]
  bf16x4 paLo[4];          // P regs from even step (q-sub 0)
  i32x4 mreg[4];           // in-flight mask row (frag(t) -> coop(t))

  auto issue_mask = [&](int qrow) {
    const int* mp_ = mask + ((size_t)(b * L + qrow)) * L + lane * 4;
#pragma unroll
    for (int ch = 0; ch < 4; ++ch)
      mreg[ch] = *reinterpret_cast<const i32x4*>(mp_ + ch * 256);
  };
  auto commit_mask = [&]() {
#pragma unroll
    for (int ch = 0; ch < 4; ++ch) {
      const u32 pk = (u32)(mreg[ch][0] & 1) | ((u32)(mreg[ch][1] & 1) << 8) |
                     ((u32)(mreg[ch][2] & 1) << 16) | ((u32)(mreg[ch][3] & 1) << 24);
      *reinterpret_cast<u32*>(&mbuf[w * MP + ch * 256 + lane * 4]) = pk;
    }
  };
  auto dma_gate = [&](int qrow, int buf) {
    const float* gp_ = gate + ((size_t)(b * L + qrow)) * L + lane * 4;
    const unsigned base = (unsigned)buf * (QS * GP * 4u) + (unsigned)w * (GP * 4u);
#pragma unroll
    for (int ch = 0; ch < 4; ++ch) {
      const unsigned off = (unsigned)__builtin_amdgcn_readfirstlane(
          (int)(base + ch * 1024u));
      __builtin_amdgcn_global_load_lds(
          (const __attribute__((address_space(1))) void*)(gp_ + ch * 256),
          (__attribute__((address_space(3))) void*)(smem + off), 16, 0, 0);
    }
  };

  // prologue: mask(0)+gate(0) staged; full drain once
  issue_mask(qbase + w);
  dma_gate(qbase + w, 0);
  commit_mask();
  asm volatile("s_waitcnt vmcnt(0) lgkmcnt(0)" ::: "memory");
  __builtin_amdgcn_s_barrier();

  for (int t = 0; t < NSTEP; ++t) {
    const int cur = t & 1, par = t & 1;
    const int q0 = qbase + t * QS;
    const bool has_next = (t + 1 < NSTEP);

    if (has_next) issue_mask(q0 + QS + w);

    // GEMM1: S[16q x 64k] = mfma(A=Q, B=K); kf transient from bf16 KT
    bf16x8 qf0, qf1;
    {
      const __bf16* qr = qt + (((size_t)(b * L + q0 + c)) << 6) + g * 8;
      qf0 = *reinterpret_cast<const bf16x8*>(qr);
      qf1 = *reinterpret_cast<const bf16x8*>(qr + 32);
    }
    f32x4 sfr[4];
#pragma unroll
    for (int ks = 0; ks < 4; ++ks) {
      const __bf16* kr = kt + (((size_t)(b * L + wkb + ks * 16 + c)) << 6) + g * 8;
      const bf16x8 kf0 = *reinterpret_cast<const bf16x8*>(kr);
      const bf16x8 kf1 = *reinterpret_cast<const bf16x8*>(kr + 32);
      f32x4 cc = {};
      cc = __builtin_amdgcn_mfma_f32_16x16x32_bf16(qf0, kf0, cc, 0, 0, 0);
      cc = __builtin_amdgcn_mfma_f32_16x16x32_bf16(qf1, kf1, cc, 0, 0, 0);
      sfr[ks] = cc;
    }

    // async gate(t+1) -> other gbuf; stays in flight across barrier A
    if (has_next) dma_gate(q0 + QS + w, cur ^ 1);

    // sigmoid in frag layout; attn in place into gbuf; P packed to regs
    bf16x8 paF[4];
#pragma unroll
    for (int ks = 0; ks < 4; ++ks) {
      f32x4 p;
#pragma unroll
      for (int r = 0; r < 4; ++r) {
        const int qloc = 4 * g + r;
        const int k = wkb + ks * 16 + c;
        const float gv = gbuf[cur * (QS * GP) + qloc * GP + k];
        const unsigned char mv = mbuf[qloc * MP + k];
        const float x = sfr[ks][r] * gv;
        p[r] = mv ? 0.0f : __builtin_amdgcn_rcpf(1.0f + __expf(-x));
        gbuf[cur * (QS * GP) + qloc * GP + k] = p[r];
      }
      if (par == 0) {
        bf16x4 q4;
#pragma unroll
        for (int r = 0; r < 4; ++r) q4[r] = (__bf16)p[r];
        paLo[ks] = q4;
      } else {
        bf16x8 pa;
#pragma unroll
        for (int r = 0; r < 4; ++r) { pa[r] = paLo[ks][r]; pa[4 + r] = (__bf16)p[r]; }
        paF[ks] = pa;
      }
    }

    // GEMM2 on odd steps: K=32 over sigma-permuted q; V gathered with sigma
    if (par == 1) {
      const int qp0 = q0 - QS;
      bf16x8 vf[4];
#pragma unroll
      for (int ds = 0; ds < 4; ++ds) {
        const __bf16* vr =
            vt + (((size_t)(b * D + ds * 16 + c)) << 10) + qp0 + 4 * g;
        const bf16x4 lo = *reinterpret_cast<const bf16x4*>(vr);
        const bf16x4 hi = *reinterpret_cast<const bf16x4*>(vr + 16);
        bf16x8 v8;
#pragma unroll
        for (int j = 0; j < 4; ++j) { v8[j] = lo[j]; v8[4 + j] = hi[j]; }
        vf[ds] = v8;
      }
#pragma unroll
      for (int ks = 0; ks < 4; ++ks)
#pragma unroll
        for (int ds = 0; ds < 4; ++ds)
          acc[ks][ds] = __builtin_amdgcn_mfma_f32_16x16x32_bf16(
              paF[ks], vf[ds], acc[ks][ds], 0, 0, 0);
    }

    // barrier A: LDS-only (attn writes visible; gate/mask reads done)
    asm volatile("s_waitcnt lgkmcnt(0)" ::: "memory");
    __builtin_amdgcn_s_barrier();

    // coop: full-row (4KB linear) attn writeback; commit mask(t+1)
    {
      const float* row = &gbuf[cur * (QS * GP) + w * GP];
      f32x4 a[4];
#pragma unroll
      for (int ch = 0; ch < 4; ++ch)
        a[ch] = *reinterpret_cast<const f32x4*>(&row[ch * 256 + lane * 4]);
      float* op = out_attn + ((size_t)(b * L + q0 + w)) * L + lane * 4;
#pragma unroll
      for (int ch = 0; ch < 4; ++ch)
        *reinterpret_cast<f32x4*>(op + ch * 256) = a[ch];
    }
    commit_mask();

    // barrier B: counted drain - DMA (older) must land, the 4 newest attn
    // stores may stay in flight; mbuf writes made visible.
    asm volatile("s_waitcnt vmcnt(4) lgkmcnt(0)" ::: "memory");
    __builtin_amdgcn_s_barrier();
  }

  // epilogue: partial-O accumulate (out_o zeroed by memset; 4-way atomics)
#pragma unroll
  for (int ks = 0; ks < 4; ++ks)
#pragma unroll
    for (int ds = 0; ds < 4; ++ds)
#pragma unroll
      for (int r = 0; r < 4; ++r)
        atomicAdd(&out_o[((size_t)(b * L + wkb + ks * 16 + 4 * g + r)) * D +
                         ds * 16 + c],
                  acc[ks][ds][r]);
}

extern "C" void kernel_launch(void* const* d_in, const int* in_sizes, int n_in,
                              void* d_out, int out_size, void* d_ws, size_t ws_size,
                              hipStream_t stream) {
  const float* q = (const float*)d_in[0];
  const float* k = (const float*)d_in[1];
  const float* v = (const float*)d_in[2];
  const int* mask = (const int*)d_in[3];
  const float* gate = (const float*)d_in[4];

  float* out_o = (float*)d_out;                 // [B, L, D]
  float* out_attn = out_o + (size_t)B * L * D;  // [B, L, L]

  __bf16* qt = (__bf16*)d_ws;                   // [B, L, D] bf16 (scaled 1/8)
  __bf16* vt = qt + (size_t)B * L * D;          // [B, D, L] bf16
  __bf16* kt = vt + (size_t)B * L * D;          // [B, L, D] bf16

  hipMemsetAsync(out_o, 0, (size_t)B * L * D * sizeof(float), stream);
  prep_kernel<<<dim3(L / 64, B), dim3(256), 0, stream>>>(q, k, v, qt, kt, vt);
  gated_attn_kernel<<<dim3(64 * QSPLIT), dim3(1024), LDS_BYTES, stream>>>(
      qt, kt, vt, mask, gate, out_o, out_attn);
}

// Round 13
// 378.866 us; speedup vs baseline: 1.0082x; 1.0082x over previous
//
#include <hip/hip_runtime.h>
#include <hip/hip_bf16.h>

namespace {
constexpr int B = 64, L = 1024, D = 64;
constexpr int QS = 16;                // q rows per step (one MFMA tile)
constexpr int QSPLIT = 4;             // q quarters -> 4-way O atomics
constexpr int QRANGE = L / QSPLIT;    // 256
constexpr int NSTEP = QRANGE / QS;    // 16
constexpr int GP = 1028;              // gbuf pitch (f32 words); 4*GP%32=16 -> 2-way max
constexpr int MP = 1040;              // mbuf pitch (bytes)
constexpr unsigned GBUF_B = 2u * QS * GP * 4u;        // 131584 (gate dbuf)
constexpr unsigned LDS_BYTES = GBUF_B + QS * MP;      // +16640 = 148224

typedef float f32x4 __attribute__((ext_vector_type(4)));
typedef int   i32x4 __attribute__((ext_vector_type(4)));
typedef __bf16 bf16x4 __attribute__((ext_vector_type(4)));
typedef __bf16 bf16x8 __attribute__((ext_vector_type(8)));
typedef unsigned int u32;
}  // namespace

// Prep: QT[b][q][d]=bf16(Q/8); KT[b][k][d]=bf16(K); VT[b][d][q]=bf16(V^T).
__global__ __launch_bounds__(256)
void prep_kernel(const float* __restrict__ qp, const float* __restrict__ kp,
                 const float* __restrict__ vp, __bf16* __restrict__ qt,
                 __bf16* __restrict__ kt, __bf16* __restrict__ vt) {
  __shared__ float t[64][65];
  const int tid = threadIdx.x;
  const int b = blockIdx.y;
  const int qb = blockIdx.x * 64;

  {  // V tile -> LDS (f32, padded)
    const int qr = tid >> 4, d0 = (tid & 15) * 4;
#pragma unroll
    for (int p = 0; p < 4; ++p) {
      f32x4 r = *reinterpret_cast<const f32x4*>(
          vp + ((size_t)(b * L + qb + p * 16 + qr)) * D + d0);
      *reinterpret_cast<f32x4*>(&t[p * 16 + qr][d0]) = r;
    }
  }
  {  // Q (scaled 1/8) and K (unscaled) bf16 row conversions
    const int qr = tid >> 2, quad = tid & 3;
    const size_t row = (size_t)(b * L + qb + qr);
    const float* qsrc = qp + row * D + quad * 16;
    const float* ksrc = kp + row * D + quad * 16;
    __bf16* qdst = qt + (row << 6) + quad * 16;
    __bf16* kdst = kt + (row << 6) + quad * 16;
#pragma unroll
    for (int h = 0; h < 2; ++h) {
      f32x4 a = *reinterpret_cast<const f32x4*>(qsrc + h * 8);
      f32x4 bb = *reinterpret_cast<const f32x4*>(qsrc + h * 8 + 4);
      a *= 0.125f; bb *= 0.125f;
      bf16x8 r;
#pragma unroll
      for (int j = 0; j < 4; ++j) { r[j] = (__bf16)a[j]; r[4 + j] = (__bf16)bb[j]; }
      *reinterpret_cast<bf16x8*>(qdst + h * 8) = r;
      f32x4 ka = *reinterpret_cast<const f32x4*>(ksrc + h * 8);
      f32x4 kb = *reinterpret_cast<const f32x4*>(ksrc + h * 8 + 4);
      bf16x8 kr;
#pragma unroll
      for (int j = 0; j < 4; ++j) { kr[j] = (__bf16)ka[j]; kr[4 + j] = (__bf16)kb[j]; }
      *reinterpret_cast<bf16x8*>(kdst + h * 8) = kr;
    }
  }
  __syncthreads();
  {  // transposed V out: VT rows = d, contiguous q
    const int qh = tid & 7, dr = tid >> 3;
#pragma unroll
    for (int p = 0; p < 2; ++p) {
      const int d = p * 32 + dr;
      bf16x8 r;
#pragma unroll
      for (int j = 0; j < 8; ++j) r[j] = (__bf16)t[qh * 8 + j][d];
      *reinterpret_cast<bf16x8*>(vt + (((size_t)(b * D + d)) << 10) + qb + qh * 8) = r;
    }
  }
}

// Main: block = (batch, 256-q quarter), FULL 1024-k rows -> gate/mask/attn
// streams are perfectly linear. 256 blocks = 1/CU, 16 waves. Per 16-q step:
// S = mfma(Q,K) (frag [q-rows][k-cols]); sigmoid in frag layout (gate from
// gbuf, mask byte from mbuf); attn written in place to gbuf, coop-written
// back as full 4KB linear rows. P stays IN REGISTERS: the sigma-permuted
// K-dim (q = 16*(j>>2)+4g+(j&3)) makes the S-frag bit-identical to GEMM2's
// A-fragment; V gathered with the same sigma from VT. Gate staged by
// global_load_lds (double-buffered), drained by counted vmcnt(4) - never 0.
__global__ __launch_bounds__(1024, 1)
void gated_attn_kernel(const __bf16* __restrict__ qt,
                       const __bf16* __restrict__ kt,
                       const __bf16* __restrict__ vt,
                       const int* __restrict__ mask,
                       const float* __restrict__ gate,
                       float* __restrict__ out_o,
                       float* __restrict__ out_attn) {
  extern __shared__ char smem[];
  float* gbuf = reinterpret_cast<float*>(smem);                     // [2][QS][GP]
  unsigned char* mbuf = reinterpret_cast<unsigned char*>(smem + GBUF_B);  // [QS][MP]

  const int tid = threadIdx.x, w = tid >> 6, lane = tid & 63;
  const int c = lane & 15, g = lane >> 4;

  // Decode: each XCD serves 8 batches; all 4 q-quarters of a batch colocate.
  const int i = blockIdx.x;
  const int b = (i & 7) * 8 + ((i >> 3) & 7);
  const int qbase = (i >> 6) * QRANGE;
  const int wkb = w * 64;  // this wave's 64-k strip

  f32x4 acc[4][4] = {};    // O[k = wkb+ks*16+4g+r][d = ds*16+c]
  bf16x4 paLo[4];          // P regs from even step (q-sub 0)
  i32x4 mreg[4];           // in-flight mask row (frag(t) -> coop(t))

  auto issue_mask = [&](int qrow) {
    const int* mp_ = mask + ((size_t)(b * L + qrow)) * L + lane * 4;
#pragma unroll
    for (int ch = 0; ch < 4; ++ch)
      mreg[ch] = *reinterpret_cast<const i32x4*>(mp_ + ch * 256);
  };
  auto commit_mask = [&]() {
#pragma unroll
    for (int ch = 0; ch < 4; ++ch) {
      const u32 pk = (u32)(mreg[ch][0] & 1) | ((u32)(mreg[ch][1] & 1) << 8) |
                     ((u32)(mreg[ch][2] & 1) << 16) | ((u32)(mreg[ch][3] & 1) << 24);
      *reinterpret_cast<u32*>(&mbuf[w * MP + ch * 256 + lane * 4]) = pk;
    }
  };
  auto dma_gate = [&](int qrow, int buf) {
    const float* gp_ = gate + ((size_t)(b * L + qrow)) * L + lane * 4;
    const unsigned base = (unsigned)buf * (QS * GP * 4u) + (unsigned)w * (GP * 4u);
#pragma unroll
    for (int ch = 0; ch < 4; ++ch) {
      const unsigned off = (unsigned)__builtin_amdgcn_readfirstlane(
          (int)(base + ch * 1024u));
      __builtin_amdgcn_global_load_lds(
          (const __attribute__((address_space(1))) void*)(gp_ + ch * 256),
          (__attribute__((address_space(3))) void*)(smem + off), 16, 0, 0);
    }
  };

  // prologue: mask(0)+gate(0) staged; full drain once
  issue_mask(qbase + w);
  dma_gate(qbase + w, 0);
  commit_mask();
  asm volatile("s_waitcnt vmcnt(0) lgkmcnt(0)" ::: "memory");
  __builtin_amdgcn_s_barrier();

  for (int t = 0; t < NSTEP; ++t) {
    const int cur = t & 1, par = t & 1;
    const int q0 = qbase + t * QS;
    const bool has_next = (t + 1 < NSTEP);

    if (has_next) issue_mask(q0 + QS + w);

    // GEMM1: S[16q x 64k] = mfma(A=Q, B=K); kf transient from bf16 KT
    bf16x8 qf0, qf1;
    {
      const __bf16* qr = qt + (((size_t)(b * L + q0 + c)) << 6) + g * 8;
      qf0 = *reinterpret_cast<const bf16x8*>(qr);
      qf1 = *reinterpret_cast<const bf16x8*>(qr + 32);
    }
    f32x4 sfr[4];
#pragma unroll
    for (int ks = 0; ks < 4; ++ks) {
      const __bf16* kr = kt + (((size_t)(b * L + wkb + ks * 16 + c)) << 6) + g * 8;
      const bf16x8 kf0 = *reinterpret_cast<const bf16x8*>(kr);
      const bf16x8 kf1 = *reinterpret_cast<const bf16x8*>(kr + 32);
      f32x4 cc = {};
      cc = __builtin_amdgcn_mfma_f32_16x16x32_bf16(qf0, kf0, cc, 0, 0, 0);
      cc = __builtin_amdgcn_mfma_f32_16x16x32_bf16(qf1, kf1, cc, 0, 0, 0);
      sfr[ks] = cc;
    }

    // async gate(t+1) -> other gbuf; stays in flight across barrier A
    if (has_next) dma_gate(q0 + QS + w, cur ^ 1);

    // sigmoid in frag layout; attn in place into gbuf; P packed to regs
    bf16x8 paF[4];
#pragma unroll
    for (int ks = 0; ks < 4; ++ks) {
      f32x4 p;
#pragma unroll
      for (int r = 0; r < 4; ++r) {
        const int qloc = 4 * g + r;
        const int k = wkb + ks * 16 + c;
        const float gv = gbuf[cur * (QS * GP) + qloc * GP + k];
        const unsigned char mv = mbuf[qloc * MP + k];
        const float x = sfr[ks][r] * gv;
        p[r] = mv ? 0.0f : __builtin_amdgcn_rcpf(1.0f + __expf(-x));
        gbuf[cur * (QS * GP) + qloc * GP + k] = p[r];
      }
      if (par == 0) {
        bf16x4 q4;
#pragma unroll
        for (int r = 0; r < 4; ++r) q4[r] = (__bf16)p[r];
        paLo[ks] = q4;
      } else {
        bf16x8 pa;
#pragma unroll
        for (int r = 0; r < 4; ++r) { pa[r] = paLo[ks][r]; pa[4 + r] = (__bf16)p[r]; }
        paF[ks] = pa;
      }
    }

    // GEMM2 on odd steps: K=32 over sigma-permuted q; V gathered with sigma
    if (par == 1) {
      const int qp0 = q0 - QS;
      bf16x8 vf[4];
#pragma unroll
      for (int ds = 0; ds < 4; ++ds) {
        const __bf16* vr =
            vt + (((size_t)(b * D + ds * 16 + c)) << 10) + qp0 + 4 * g;
        const bf16x4 lo = *reinterpret_cast<const bf16x4*>(vr);
        const bf16x4 hi = *reinterpret_cast<const bf16x4*>(vr + 16);
        bf16x8 v8;
#pragma unroll
        for (int j = 0; j < 4; ++j) { v8[j] = lo[j]; v8[4 + j] = hi[j]; }
        vf[ds] = v8;
      }
#pragma unroll
      for (int ks = 0; ks < 4; ++ks)
#pragma unroll
        for (int ds = 0; ds < 4; ++ds)
          acc[ks][ds] = __builtin_amdgcn_mfma_f32_16x16x32_bf16(
              paF[ks], vf[ds], acc[ks][ds], 0, 0, 0);
    }

    // barrier A: LDS-only (attn writes visible; gate/mask reads done)
    asm volatile("s_waitcnt lgkmcnt(0)" ::: "memory");
    __builtin_amdgcn_s_barrier();

    // coop: full-row (4KB linear) attn writeback; commit mask(t+1)
    {
      const float* row = &gbuf[cur * (QS * GP) + w * GP];
      f32x4 a[4];
#pragma unroll
      for (int ch = 0; ch < 4; ++ch)
        a[ch] = *reinterpret_cast<const f32x4*>(&row[ch * 256 + lane * 4]);
      float* op = out_attn + ((size_t)(b * L + q0 + w)) * L + lane * 4;
#pragma unroll
      for (int ch = 0; ch < 4; ++ch)
        *reinterpret_cast<f32x4*>(op + ch * 256) = a[ch];
    }
    commit_mask();

    // barrier B: counted drain - DMA (older) must land, the 4 newest attn
    // stores may stay in flight; mbuf writes made visible.
    asm volatile("s_waitcnt vmcnt(4) lgkmcnt(0)" ::: "memory");
    __builtin_amdgcn_s_barrier();
  }

  // epilogue: partial-O accumulate (out_o zeroed by memset; 4-way atomics)
#pragma unroll
  for (int ks = 0; ks < 4; ++ks)
#pragma unroll
    for (int ds = 0; ds < 4; ++ds)
#pragma unroll
      for (int r = 0; r < 4; ++r)
        atomicAdd(&out_o[((size_t)(b * L + wkb + ks * 16 + 4 * g + r)) * D +
                         ds * 16 + c],
                  acc[ks][ds][r]);
}

extern "C" void kernel_launch(void* const* d_in, const int* in_sizes, int n_in,
                              void* d_out, int out_size, void* d_ws, size_t ws_size,
                              hipStream_t stream) {
  const float* q = (const float*)d_in[0];
  const float* k = (const float*)d_in[1];
  const float* v = (const float*)d_in[2];
  const int* mask = (const int*)d_in[3];
  const float* gate = (const float*)d_in[4];

  float* out_o = (float*)d_out;                 // [B, L, D]
  float* out_attn = out_o + (size_t)B * L * D;  // [B, L, L]

  __bf16* qt = (__bf16*)d_ws;                   // [B, L, D] bf16 (scaled 1/8)
  __bf16* vt = qt + (size_t)B * L * D;          // [B, D, L] bf16
  __bf16* kt = vt + (size_t)B * L * D;          // [B, L, D] bf16

  hipMemsetAsync(out_o, 0, (size_t)B * L * D * sizeof(float), stream);
  prep_kernel<<<dim3(L / 64, B), dim3(256), 0, stream>>>(q, k, v, qt, kt, vt);
  gated_attn_kernel<<<dim3(64 * QSPLIT), dim3(1024), LDS_BYTES, stream>>>(
      qt, kt, vt, mask, gate, out_o, out_attn);
}